// Round 6
// baseline (351.036 us; speedup 1.0000x reference)
//
#include <hip/hip_runtime.h>
#include <stdint.h>

typedef unsigned short u16;
typedef __attribute__((ext_vector_type(4))) float f32x4;
typedef __attribute__((ext_vector_type(16))) float f32x16;
typedef __attribute__((ext_vector_type(8))) __bf16 bf16x8;
typedef __attribute__((ext_vector_type(8))) u16 u16x8;
typedef __attribute__((ext_vector_type(4))) u16 u16x4;

static constexpr int kB = 4, kS = 2048, kD = 1024, kH = 16, kHD = 64;
static constexpr int M1 = kB * kS;   // 8192
static constexpr int N1 = 3 * kD;    // 3072
static constexpr int K1 = kD;        // 1024

// 1/sqrt(64) * log2(e), folded into Q at GEMM1 epilogue
#define SCLF 0.18033688011112042f
#define MFMA32(a, b, c) __builtin_amdgcn_mfma_f32_32x32x16_bf16((a), (b), (c), 0, 0, 0)

union U4 { unsigned u[4]; bf16x8 v; };

__device__ __forceinline__ u16 f2bf(float f) {
  union { float f; uint32_t u; } c; c.f = f;
  uint32_t u = c.u + 0x7FFFu + ((c.u >> 16) & 1u);   // RNE
  return (u16)(u >> 16);
}

__device__ __forceinline__ unsigned pkbf(float a, float b) {
  union { __bf16 h[2]; unsigned u; } c;
  c.h[0] = (__bf16)a; c.h[1] = (__bf16)b;
  return c.u;
}

__device__ __forceinline__ f32x16 zero16() {
  f32x16 v;
#pragma unroll
  for (int i = 0; i < 16; ++i) v[i] = 0.f;
  return v;
}

__device__ __forceinline__ void gload_lds16(const u16* g, u16* l) {
  __builtin_amdgcn_global_load_lds(
      (const __attribute__((address_space(1))) unsigned int*)g,
      (__attribute__((address_space(3))) unsigned int*)l, 16, 0, 0);
}

// P redistribution: pp[16] (C-layout rows) -> two B-frags (keys base+0..15, +16..31)
__device__ __forceinline__ void packP(const float* pp, int hi, U4& f0, U4& f1) {
  const unsigned qa0 = pkbf(pp[0], pp[1]),   qa1 = pkbf(pp[2], pp[3]);
  const unsigned qb0 = pkbf(pp[4], pp[5]),   qb1 = pkbf(pp[6], pp[7]);
  const unsigned qc0 = pkbf(pp[8], pp[9]),   qc1 = pkbf(pp[10], pp[11]);
  const unsigned qd0 = pkbf(pp[12], pp[13]), qd1 = pkbf(pp[14], pp[15]);
  const unsigned xa0 = __shfl_xor(qa0, 32, 64), xa1 = __shfl_xor(qa1, 32, 64);
  const unsigned xb0 = __shfl_xor(qb0, 32, 64), xb1 = __shfl_xor(qb1, 32, 64);
  const unsigned xc0 = __shfl_xor(qc0, 32, 64), xc1 = __shfl_xor(qc1, 32, 64);
  const unsigned xd0 = __shfl_xor(qd0, 32, 64), xd1 = __shfl_xor(qd1, 32, 64);
  f0.u[0] = hi ? xb0 : qa0; f0.u[1] = hi ? xb1 : qa1;
  f0.u[2] = hi ? qb0 : xa0; f0.u[3] = hi ? qb1 : xa1;
  f1.u[0] = hi ? xd0 : qc0; f1.u[1] = hi ? xd1 : qc1;
  f1.u[2] = hi ? qd0 : xc0; f1.u[3] = hi ? qd1 : xc1;
}

// ---------------- cast kernels ----------------
__global__ __launch_bounds__(256) void k_cast_x(const float* __restrict__ x,
                                                u16* __restrict__ o) {
  int i = (blockIdx.x * 256 + threadIdx.x) * 4;
  f32x4 v = *(const f32x4*)(x + i);
  u16x4 r;
  r[0] = f2bf(v[0]); r[1] = f2bf(v[1]); r[2] = f2bf(v[2]); r[3] = f2bf(v[3]);
  *(u16x4*)(o + i) = r;
}

// w: [K][N] f32  ->  wt: [N][K] bf16   (B^T layout for GEMM)
__global__ __launch_bounds__(256) void k_transpose_cast(const float* __restrict__ w,
                                                        u16* __restrict__ wt,
                                                        int K, int N) {
  __shared__ float t[32][33];
  const int n0 = blockIdx.x * 32, k0 = blockIdx.y * 32;
  const int tx = threadIdx.x & 31, ty = threadIdx.x >> 5;
  for (int r = ty; r < 32; r += 8)
    t[r][tx] = w[(size_t)(k0 + r) * N + n0 + tx];
  __syncthreads();
  for (int r = ty; r < 32; r += 8)
    wt[(size_t)(n0 + r) * K + k0 + tx] = f2bf(t[tx][r]);
}

// ---------------- GEMM (A row-major MxK, BT row-major NxK) ----------------
// XCD swizzle: contiguous tile chunk per XCD (nwg % 8 == 0 for all our grids)
template <int MODE>
__global__ __launch_bounds__(256) void k_gemm_bt(const u16* __restrict__ A,
                                                 const u16* __restrict__ BT,
                                                 u16* __restrict__ obf,
                                                 float* __restrict__ of,
                                                 int M, int N, int K) {
  typedef __attribute__((ext_vector_type(4))) float f4;
  __shared__ __align__(16) u16 As[128 * 32];
  __shared__ __align__(16) u16 Bs[128 * 32];
  const int tid = threadIdx.x;
  const int wave = tid >> 6, lane = tid & 63;
  const int l15 = lane & 15, l16 = lane >> 4;

  const int bid = blockIdx.y * gridDim.x + blockIdx.x;
  const int qch = (gridDim.x * gridDim.y) >> 3;
  const int swz = (bid & 7) * qch + (bid >> 3);
  const int row0 = (swz / gridDim.x) * 128, col0 = (swz % gridDim.x) * 128;
  const int wm = (wave >> 1) * 64, wn = (wave & 1) * 64;

  f4 acc[4][4];
#pragma unroll
  for (int i = 0; i < 4; ++i)
#pragma unroll
    for (int j = 0; j < 4; ++j) acc[i][j] = f4{0.f, 0.f, 0.f, 0.f};

  const int e0 = wave * 512 + lane * 8;
  const int r0 = e0 >> 5, c0 = e0 & 31;
  const int e1 = e0 + 2048;
  const int r1 = e1 >> 5, c1 = e1 & 31;
  const u16* Ab = A + (size_t)row0 * K;
  const u16* Bb = BT + (size_t)col0 * K;

  for (int kt = 0; kt < K; kt += 32) {
    gload_lds16(Ab + (size_t)r0 * K + kt + c0, &As[wave * 512]);
    gload_lds16(Ab + (size_t)r1 * K + kt + c1, &As[2048 + wave * 512]);
    gload_lds16(Bb + (size_t)r0 * K + kt + c0, &Bs[wave * 512]);
    gload_lds16(Bb + (size_t)r1 * K + kt + c1, &Bs[2048 + wave * 512]);
    __syncthreads();
    bf16x8 af[4], bfv[4];
#pragma unroll
    for (int f = 0; f < 4; ++f) {
      af[f]  = *(const bf16x8*)&As[(wm + f * 16 + l15) * 32 + l16 * 8];
      bfv[f] = *(const bf16x8*)&Bs[(wn + f * 16 + l15) * 32 + l16 * 8];
    }
#pragma unroll
    for (int fm = 0; fm < 4; ++fm)
#pragma unroll
      for (int fn = 0; fn < 4; ++fn)
        acc[fm][fn] = __builtin_amdgcn_mfma_f32_16x16x32_bf16(af[fm], bfv[fn],
                                                              acc[fm][fn], 0, 0, 0);
    __syncthreads();
  }

#pragma unroll
  for (int fm = 0; fm < 4; ++fm)
#pragma unroll
    for (int fn = 0; fn < 4; ++fn) {
      const int n = col0 + wn + fn * 16 + l15;
#pragma unroll
      for (int j = 0; j < 4; ++j) {
        const int m = row0 + wm + fm * 16 + l16 * 4 + j;
        float v = acc[fm][fn][j];
        if constexpr (MODE == 0) {
          const int which = n >> 10, d = n & 1023;
          const int h = d >> 6, hd = d & 63;
          const int b = m >> 11, s = m & 2047;
          if (which == 0) v *= SCLF;   // fold softmax scale (log2 dom) into Q
          obf[((((size_t)which * 4 + b) * 16 + h) * 2048 + s) * 64 + hd] = f2bf(v);
        } else {
          of[(size_t)m * N + n] = v;
        }
      }
    }
}

// ---------------- flash attention v5 (swapped 32x32, KVBLK=64, 1 superblock/block)
// grid: 1024 blocks, 1D. Decode: xcd=bid&7, bh=xcd*8+(idx>>4), qsup=15-(idx&15)
//   -> all 16 q-superblocks of one head on one XCD (K/V L2-resident);
//   whole grid co-resident at 4 blocks/CU (32KB LDS, <=128 VGPR) so the
//   qsup work imbalance is absorbed by SIMD-level interleaving.
// S^T = mfma(K, Q): lane owns q = qstart + (lane&31).
// O^T = mfma(Vt_frag, P_frag): m/l/rescale lane-local; l cross-half merged
// once in epilogue. Defer-max: skip rescale+shfl when max grows <= 8 (log2).
__global__ __launch_bounds__(256, 4) void k_attn(const u16* __restrict__ Qg,
                                                 const u16* __restrict__ Kg,
                                                 const u16* __restrict__ Vg,
                                                 u16* __restrict__ ctx) {
  __shared__ __align__(16) u16 Ks[2][64 * 64];        // 16 KB
  __shared__ __align__(16) unsigned Vt[2][64 * 32];   // 16 KB  [d][kp]

  const int bid = blockIdx.x;
  const int xcd = bid & 7, idx = bid >> 3;
  const int bh = xcd * 8 + (idx >> 4);
  const int qsup = 15 - (idx & 15);          // largest extent first within head
  const int bb = bh >> 4, hh = bh & 15;
  const int tid = threadIdx.x;
  const int wave = tid >> 6, lane = tid & 63;
  const int l31 = lane & 31, hi = lane >> 5;
  const int s0 = qsup * 128;
  const int qstart = s0 + wave * 32;
  const int ntiles = 2 * qsup + 2;           // 64-key tiles

  const u16* Qb = Qg + (size_t)bh * kS * kHD;
  const u16* Kb = Kg + (size_t)bh * kS * kHD;
  const u16* Vb = Vg + (size_t)bh * kS * kHD;

  const int do8 = tid & 7, kp = tid >> 3;        // V staging: d-slice, key-pair
  const int kkey8 = lane >> 3, ksl = lane & 7;   // K staging lane map
  const int swzA = (((l31 & 7) ^ (l31 >> 3)) << 2);

  // per-thread V LDS store offsets (constant across tiles)
  unsigned voff[8];
#pragma unroll
  for (int i = 0; i < 8; ++i) {
    const int d = do8 * 8 + i;
    voff[i] = d * 32 + (kp ^ ((((d & 7) ^ (d >> 3))) << 2));
  }

  // Q B-frags: row q = qstart + l31, k = ds*16 + hi*8 + i
  bf16x8 bq[4];
#pragma unroll
  for (int ds = 0; ds < 4; ++ds)
    bq[ds] = *(const bf16x8*)(Qb + (size_t)(qstart + l31) * 64 + ds * 16 + hi * 8);

  f32x16 acco0 = zero16(), acco1 = zero16();
  float mrow = -3e38f, lrowh = 0.f;

  // ---- prologue: V(0)->Vt[0]; V(1)->regs; K(0) gloads ----
  u16x8 va, vb;
  {
    const u16* vs = Vb + (size_t)(2 * kp) * 64 + do8 * 8;
    va = *(const u16x8*)vs; vb = *(const u16x8*)(vs + 64);
  }
#pragma unroll
  for (int i = 0; i < 8; ++i)
    Vt[0][voff[i]] = (unsigned)va[i] | ((unsigned)vb[i] << 16);
  {
    const u16* vs = Vb + (size_t)(64 + 2 * kp) * 64 + do8 * 8;
    va = *(const u16x8*)vs; vb = *(const u16x8*)(vs + 64);
  }
#pragma unroll
  for (int rep = 0; rep < 2; ++rep) {
    const int key = wave * 16 + rep * 8 + kkey8;
    gload_lds16(Kb + (size_t)key * 64 + (ksl ^ (key & 7)) * 8,
                &Ks[0][(wave * 2 + rep) * 512]);
  }

  for (int t = 0; t < ntiles; ++t) {
    const int kv0 = t * 64;
    __syncthreads();  // drains K(t) gloads; syncs V(t) stores; prev reads done

    if (t + 1 < ntiles) {
      const int nb = (t + 1) & 1;
#pragma unroll
      for (int i = 0; i < 8; ++i)
        Vt[nb][voff[i]] = (unsigned)va[i] | ((unsigned)vb[i] << 16);
#pragma unroll
      for (int rep = 0; rep < 2; ++rep) {
        const int key = wave * 16 + rep * 8 + kkey8;
        gload_lds16(Kb + (size_t)(kv0 + 64 + key) * 64 + (ksl ^ (key & 7)) * 8,
                    &Ks[nb][(wave * 2 + rep) * 512]);
      }
      if (t + 2 < ntiles) {
        const u16* vs = Vb + (size_t)(kv0 + 128 + 2 * kp) * 64 + do8 * 8;
        va = *(const u16x8*)vs; vb = *(const u16x8*)(vs + 64);
      }
    }

    if (kv0 > qstart + 31) continue;  // wave-uniform skip (barrier already done)

    const u16* Ksb = &Ks[t & 1][0];
    const unsigned* Vtb = &Vt[t & 1][0];
    const int qv = qstart + l31;
    const bool pres1 = (kv0 + 32 <= qstart + 31);

    // ---- QK^T ----
    f32x16 st0 = zero16(), st1 = zero16();
    __builtin_amdgcn_s_setprio(1);
#pragma unroll
    for (int ds = 0; ds < 4; ++ds) {
      const int sl = (((ds << 1) | hi) ^ (l31 & 7)) * 8;
      bf16x8 ak0 = *(const bf16x8*)&Ksb[l31 * 64 + sl];
      st0 = MFMA32(ak0, bq[ds], st0);
      if (pres1) {
        bf16x8 ak1 = *(const bf16x8*)&Ksb[(32 + l31) * 64 + sl];
        st1 = MFMA32(ak1, bq[ds], st1);
      }
    }
    __builtin_amdgcn_s_setprio(0);

    // ---- mask into st, local max ----
    float tl = -3e38f;
    if (kv0 + 31 > qstart) {
      const int kb0 = kv0 + 4 * hi;
#pragma unroll
      for (int r = 0; r < 16; ++r) {
        const int key = kb0 + (r & 3) + 8 * (r >> 2);
        float v = st0[r];
        v = (key <= qv) ? v : -3e38f;
        st0[r] = v;
        tl = fmaxf(tl, v);
      }
    } else {
#pragma unroll
      for (int r = 0; r < 16; ++r) tl = fmaxf(tl, st0[r]);
    }
    if (pres1) {
      if (kv0 + 63 > qstart) {
        const int kb1 = kv0 + 32 + 4 * hi;
#pragma unroll
        for (int r = 0; r < 16; ++r) {
          const int key = kb1 + (r & 3) + 8 * (r >> 2);
          float v = st1[r];
          v = (key <= qv) ? v : -3e38f;
          st1[r] = v;
          tl = fmaxf(tl, v);
        }
      } else {
#pragma unroll
        for (int r = 0; r < 16; ++r) tl = fmaxf(tl, st1[r]);
      }
    }

    // ---- defer-max decision ----
    float mn;
    if (__all(tl <= mrow + 8.0f)) {
      mn = mrow;                      // deferred: no shfl, no rescale
    } else {
      const float tj = fmaxf(tl, __shfl_xor(tl, 32, 64));
      mn = fmaxf(mrow, tj);
      const float al = exp2f(mrow - mn);
      mrow = mn;
      lrowh *= al;
#pragma unroll
      for (int r = 0; r < 16; ++r) { acco0[r] *= al; acco1[r] *= al; }
    }

    // ---- chunk 0 (keys kv0 .. kv0+31) ----
    {
      float pp[16];
#pragma unroll
      for (int r = 0; r < 16; ++r) pp[r] = exp2f(st0[r] - mn);
      const float t0 = (pp[0] + pp[1]) + (pp[2] + pp[3]);
      const float t1 = (pp[4] + pp[5]) + (pp[6] + pp[7]);
      const float t2 = (pp[8] + pp[9]) + (pp[10] + pp[11]);
      const float t3 = (pp[12] + pp[13]) + (pp[14] + pp[15]);
      lrowh += (t0 + t1) + (t2 + t3);
      U4 f0, f1;
      packP(pp, hi, f0, f1);
      __builtin_amdgcn_s_setprio(1);
      {
        const int dbase = l31 * 32, sz = swzA;
        const bf16x8 vfa = *(const bf16x8*)&Vtb[dbase + ((hi * 4) ^ sz)];
        acco0 = MFMA32(vfa, f0.v, acco0);
        const bf16x8 vfb = *(const bf16x8*)&Vtb[dbase + ((8 + hi * 4) ^ sz)];
        acco0 = MFMA32(vfb, f1.v, acco0);
      }
      {
        const int dbase = (32 + l31) * 32, sz = swzA ^ 16;
        const bf16x8 vfa = *(const bf16x8*)&Vtb[dbase + ((hi * 4) ^ sz)];
        acco1 = MFMA32(vfa, f0.v, acco1);
        const bf16x8 vfb = *(const bf16x8*)&Vtb[dbase + ((8 + hi * 4) ^ sz)];
        acco1 = MFMA32(vfb, f1.v, acco1);
      }
      __builtin_amdgcn_s_setprio(0);
    }
    // ---- chunk 1 (keys kv0+32 .. kv0+63) ----
    if (pres1) {
      float pp[16];
#pragma unroll
      for (int r = 0; r < 16; ++r) pp[r] = exp2f(st1[r] - mn);
      const float t0 = (pp[0] + pp[1]) + (pp[2] + pp[3]);
      const float t1 = (pp[4] + pp[5]) + (pp[6] + pp[7]);
      const float t2 = (pp[8] + pp[9]) + (pp[10] + pp[11]);
      const float t3 = (pp[12] + pp[13]) + (pp[14] + pp[15]);
      lrowh += (t0 + t1) + (t2 + t3);
      U4 f0, f1;
      packP(pp, hi, f0, f1);
      __builtin_amdgcn_s_setprio(1);
      {
        const int dbase = l31 * 32, sz = swzA;
        const bf16x8 vfa = *(const bf16x8*)&Vtb[dbase + ((16 + hi * 4) ^ sz)];
        acco0 = MFMA32(vfa, f0.v, acco0);
        const bf16x8 vfb = *(const bf16x8*)&Vtb[dbase + ((24 + hi * 4) ^ sz)];
        acco0 = MFMA32(vfb, f1.v, acco0);
      }
      {
        const int dbase = (32 + l31) * 32, sz = swzA ^ 16;
        const bf16x8 vfa = *(const bf16x8*)&Vtb[dbase + ((16 + hi * 4) ^ sz)];
        acco1 = MFMA32(vfa, f0.v, acco1);
        const bf16x8 vfb = *(const bf16x8*)&Vtb[dbase + ((24 + hi * 4) ^ sz)];
        acco1 = MFMA32(vfb, f1.v, acco1);
      }
      __builtin_amdgcn_s_setprio(0);
    }
  }

  // ---- epilogue: merge l across halves once; write O^T rows ----
  const float lrow = lrowh + __shfl_xor(lrowh, 32, 64);
  const float rl = 1.0f / lrow;
  u16* orow = ctx + ((size_t)bb * kS + (qstart + l31)) * kD + hh * 64;
#pragma unroll
  for (int rq = 0; rq < 4; ++rq) {
    u16x4 pk0, pk1;
#pragma unroll
    for (int c = 0; c < 4; ++c) {
      pk0[c] = f2bf(acco0[rq * 4 + c] * rl);
      pk1[c] = f2bf(acco1[rq * 4 + c] * rl);
    }
    *(u16x4*)&orow[rq * 8 + hi * 4] = pk0;
    *(u16x4*)&orow[32 + rq * 8 + hi * 4] = pk1;
  }
}

// ---------------- launcher ----------------
extern "C" void kernel_launch(void* const* d_in, const int* in_sizes, int n_in,
                              void* d_out, int out_size, void* d_ws, size_t ws_size,
                              hipStream_t stream) {
  const float* x     = (const float*)d_in[0];
  const float* w_qkv = (const float*)d_in[1];
  const float* w_out = (const float*)d_in[2];
  float* out = (float*)d_out;

  u16* ws    = (u16*)d_ws;
  u16* x_bf  = ws;                                  // 8192*1024
  u16* wqkvT = x_bf + (size_t)M1 * K1;              // 3072*1024
  u16* woutT = wqkvT + (size_t)N1 * K1;             // 1024*1024
  u16* qkv   = woutT + (size_t)kD * kD;             // 3 * 64*2048*64
  u16* ctx   = qkv + (size_t)3 * kB * kH * kS * kHD;  // 8192*1024

  k_cast_x<<<M1 * K1 / 1024, 256, 0, stream>>>(x, x_bf);
  k_transpose_cast<<<dim3(N1 / 32, K1 / 32), 256, 0, stream>>>(w_qkv, wqkvT, K1, N1);
  k_transpose_cast<<<dim3(kD / 32, kD / 32), 256, 0, stream>>>(w_out, woutT, kD, kD);

  k_gemm_bt<0><<<dim3(N1 / 128, M1 / 128), 256, 0, stream>>>(x_bf, wqkvT, qkv, nullptr,
                                                             M1, N1, K1);

  const u16* Qg = qkv;
  const u16* Kg = qkv + (size_t)kB * kH * kS * kHD;
  const u16* Vg = qkv + (size_t)2 * kB * kH * kS * kHD;
  k_attn<<<dim3(1024), 256, 0, stream>>>(Qg, Kg, Vg, ctx);

  k_gemm_bt<1><<<dim3(kD / 128, M1 / 128), 256, 0, stream>>>(ctx, woutT, nullptr, out,
                                                             M1, kD, K1);
}

// Round 7
// 252.658 us; speedup vs baseline: 1.3894x; 1.3894x over previous
//
#include <hip/hip_runtime.h>
#include <stdint.h>

typedef unsigned short u16;
typedef __attribute__((ext_vector_type(4))) float f32x4;
typedef __attribute__((ext_vector_type(16))) float f32x16;
typedef __attribute__((ext_vector_type(8))) __bf16 bf16x8;
typedef __attribute__((ext_vector_type(8))) u16 u16x8;
typedef __attribute__((ext_vector_type(4))) u16 u16x4;

static constexpr int kB = 4, kS = 2048, kD = 1024, kH = 16, kHD = 64;
static constexpr int M1 = kB * kS;   // 8192
static constexpr int N1 = 3 * kD;    // 3072
static constexpr int K1 = kD;        // 1024

// 1/sqrt(64) * log2(e), folded into Q at GEMM1 epilogue
#define SCLF 0.18033688011112042f
#define MFMA32(a, b, c) __builtin_amdgcn_mfma_f32_32x32x16_bf16((a), (b), (c), 0, 0, 0)

union U4 { unsigned u[4]; bf16x8 v; };

__device__ __forceinline__ u16 f2bf(float f) {
  union { float f; uint32_t u; } c; c.f = f;
  uint32_t u = c.u + 0x7FFFu + ((c.u >> 16) & 1u);   // RNE
  return (u16)(u >> 16);
}

__device__ __forceinline__ unsigned pkbf(float a, float b) {
  union { __bf16 h[2]; unsigned u; } c;
  c.h[0] = (__bf16)a; c.h[1] = (__bf16)b;
  return c.u;
}

__device__ __forceinline__ f32x16 zero16() {
  f32x16 v;
#pragma unroll
  for (int i = 0; i < 16; ++i) v[i] = 0.f;
  return v;
}

__device__ __forceinline__ void gload_lds16(const u16* g, u16* l) {
  __builtin_amdgcn_global_load_lds(
      (const __attribute__((address_space(1))) unsigned int*)g,
      (__attribute__((address_space(3))) unsigned int*)l, 16, 0, 0);
}

// P redistribution: p[16] (C-layout rows, already exp'd) -> two B-frags
__device__ __forceinline__ void packP(const f32x16& pp, int hi, U4& f0, U4& f1) {
  const unsigned qa0 = pkbf(pp[0], pp[1]),   qa1 = pkbf(pp[2], pp[3]);
  const unsigned qb0 = pkbf(pp[4], pp[5]),   qb1 = pkbf(pp[6], pp[7]);
  const unsigned qc0 = pkbf(pp[8], pp[9]),   qc1 = pkbf(pp[10], pp[11]);
  const unsigned qd0 = pkbf(pp[12], pp[13]), qd1 = pkbf(pp[14], pp[15]);
  const unsigned xa0 = __shfl_xor(qa0, 32, 64), xa1 = __shfl_xor(qa1, 32, 64);
  const unsigned xb0 = __shfl_xor(qb0, 32, 64), xb1 = __shfl_xor(qb1, 32, 64);
  const unsigned xc0 = __shfl_xor(qc0, 32, 64), xc1 = __shfl_xor(qc1, 32, 64);
  const unsigned xd0 = __shfl_xor(qd0, 32, 64), xd1 = __shfl_xor(qd1, 32, 64);
  f0.u[0] = hi ? xb0 : qa0; f0.u[1] = hi ? xb1 : qa1;
  f0.u[2] = hi ? qb0 : xa0; f0.u[3] = hi ? qb1 : xa1;
  f1.u[0] = hi ? xd0 : qc0; f1.u[1] = hi ? xd1 : qc1;
  f1.u[2] = hi ? qd0 : xc0; f1.u[3] = hi ? qd1 : xc1;
}

// ---------------- cast kernels ----------------
__global__ __launch_bounds__(256) void k_cast_x(const float* __restrict__ x,
                                                u16* __restrict__ o) {
  int i = (blockIdx.x * 256 + threadIdx.x) * 4;
  f32x4 v = *(const f32x4*)(x + i);
  u16x4 r;
  r[0] = f2bf(v[0]); r[1] = f2bf(v[1]); r[2] = f2bf(v[2]); r[3] = f2bf(v[3]);
  *(u16x4*)(o + i) = r;
}

// w: [K][N] f32  ->  wt: [N][K] bf16   (B^T layout for GEMM)
__global__ __launch_bounds__(256) void k_transpose_cast(const float* __restrict__ w,
                                                        u16* __restrict__ wt,
                                                        int K, int N) {
  __shared__ float t[32][33];
  const int n0 = blockIdx.x * 32, k0 = blockIdx.y * 32;
  const int tx = threadIdx.x & 31, ty = threadIdx.x >> 5;
  for (int r = ty; r < 32; r += 8)
    t[r][tx] = w[(size_t)(k0 + r) * N + n0 + tx];
  __syncthreads();
  for (int r = ty; r < 32; r += 8)
    wt[(size_t)(n0 + r) * K + k0 + tx] = f2bf(t[tx][r]);
}

// ---------------- GEMM (A row-major MxK, BT row-major NxK) ----------------
// XCD swizzle: contiguous tile chunk per XCD (nwg % 8 == 0 for all our grids)
template <int MODE>
__global__ __launch_bounds__(256) void k_gemm_bt(const u16* __restrict__ A,
                                                 const u16* __restrict__ BT,
                                                 u16* __restrict__ obf,
                                                 float* __restrict__ of,
                                                 int M, int N, int K) {
  typedef __attribute__((ext_vector_type(4))) float f4;
  __shared__ __align__(16) u16 As[128 * 32];
  __shared__ __align__(16) u16 Bs[128 * 32];
  const int tid = threadIdx.x;
  const int wave = tid >> 6, lane = tid & 63;
  const int l15 = lane & 15, l16 = lane >> 4;

  const int bid = blockIdx.y * gridDim.x + blockIdx.x;
  const int qch = (gridDim.x * gridDim.y) >> 3;
  const int swz = (bid & 7) * qch + (bid >> 3);
  const int row0 = (swz / gridDim.x) * 128, col0 = (swz % gridDim.x) * 128;
  const int wm = (wave >> 1) * 64, wn = (wave & 1) * 64;

  f4 acc[4][4];
#pragma unroll
  for (int i = 0; i < 4; ++i)
#pragma unroll
    for (int j = 0; j < 4; ++j) acc[i][j] = f4{0.f, 0.f, 0.f, 0.f};

  const int e0 = wave * 512 + lane * 8;
  const int r0 = e0 >> 5, c0 = e0 & 31;
  const int e1 = e0 + 2048;
  const int r1 = e1 >> 5, c1 = e1 & 31;
  const u16* Ab = A + (size_t)row0 * K;
  const u16* Bb = BT + (size_t)col0 * K;

  for (int kt = 0; kt < K; kt += 32) {
    gload_lds16(Ab + (size_t)r0 * K + kt + c0, &As[wave * 512]);
    gload_lds16(Ab + (size_t)r1 * K + kt + c1, &As[2048 + wave * 512]);
    gload_lds16(Bb + (size_t)r0 * K + kt + c0, &Bs[wave * 512]);
    gload_lds16(Bb + (size_t)r1 * K + kt + c1, &Bs[2048 + wave * 512]);
    __syncthreads();
    bf16x8 af[4], bfv[4];
#pragma unroll
    for (int f = 0; f < 4; ++f) {
      af[f]  = *(const bf16x8*)&As[(wm + f * 16 + l15) * 32 + l16 * 8];
      bfv[f] = *(const bf16x8*)&Bs[(wn + f * 16 + l15) * 32 + l16 * 8];
    }
#pragma unroll
    for (int fm = 0; fm < 4; ++fm)
#pragma unroll
      for (int fn = 0; fn < 4; ++fn)
        acc[fm][fn] = __builtin_amdgcn_mfma_f32_16x16x32_bf16(af[fm], bfv[fn],
                                                              acc[fm][fn], 0, 0, 0);
    __syncthreads();
  }

#pragma unroll
  for (int fm = 0; fm < 4; ++fm)
#pragma unroll
    for (int fn = 0; fn < 4; ++fn) {
      const int n = col0 + wn + fn * 16 + l15;
#pragma unroll
      for (int j = 0; j < 4; ++j) {
        const int m = row0 + wm + fm * 16 + l16 * 4 + j;
        float v = acc[fm][fn][j];
        if constexpr (MODE == 0) {
          const int which = n >> 10, d = n & 1023;
          const int h = d >> 6, hd = d & 63;
          const int b = m >> 11, s = m & 2047;
          if (which == 0) v *= SCLF;   // fold softmax scale (log2 dom) into Q
          obf[((((size_t)which * 4 + b) * 16 + h) * 2048 + s) * 64 + hd] = f2bf(v);
        } else {
          of[(size_t)m * N + n] = v;
        }
      }
    }
}

// ---------------- flash attention v6 (v5 geometry, 3 waves/SIMD, no spill) ----
// grid: 1024 blocks, 1D. Decode: xcd=bid&7, bh=xcd*8+(idx>>4), qsup=15-(idx&15).
// __launch_bounds__(256,3): 512/3=170 unified regs -- fits the ~150 live state
// (round-6's (256,4) forced 64 arch VGPRs -> 66MB scratch spill, 2.4x slower).
__global__ __launch_bounds__(256, 3) void k_attn(const u16* __restrict__ Qg,
                                                 const u16* __restrict__ Kg,
                                                 const u16* __restrict__ Vg,
                                                 u16* __restrict__ ctx) {
  __shared__ __align__(16) u16 Ks[2][64 * 64];        // 16 KB
  __shared__ __align__(16) unsigned Vt[2][64 * 32];   // 16 KB  [d][kp]

  const int bid = blockIdx.x;
  const int xcd = bid & 7, idx = bid >> 3;
  const int bh = xcd * 8 + (idx >> 4);
  const int qsup = 15 - (idx & 15);          // largest extent first within head
  const int bb = bh >> 4, hh = bh & 15;
  const int tid = threadIdx.x;
  const int wave = tid >> 6, lane = tid & 63;
  const int l31 = lane & 31, hi = lane >> 5;
  const int s0 = qsup * 128;
  const int qstart = s0 + wave * 32;
  const int ntiles = 2 * qsup + 2;           // 64-key tiles

  const u16* Qb = Qg + (size_t)bh * kS * kHD;
  const u16* Kb = Kg + (size_t)bh * kS * kHD;
  const u16* Vb = Vg + (size_t)bh * kS * kHD;

  const int do8 = tid & 7, kp = tid >> 3;        // V staging: d-slice, key-pair
  const int kkey8 = lane >> 3, ksl = lane & 7;   // K staging lane map
  const int swzA = (((l31 & 7) ^ (l31 >> 3)) << 2);

  // per-thread V LDS store offsets (constant across tiles)
  unsigned voff[8];
#pragma unroll
  for (int i = 0; i < 8; ++i) {
    const int d = do8 * 8 + i;
    voff[i] = d * 32 + (kp ^ ((((d & 7) ^ (d >> 3))) << 2));
  }

  // Q B-frags: row q = qstart + l31, k = ds*16 + hi*8 + i
  bf16x8 bq[4];
#pragma unroll
  for (int ds = 0; ds < 4; ++ds)
    bq[ds] = *(const bf16x8*)(Qb + (size_t)(qstart + l31) * 64 + ds * 16 + hi * 8);

  f32x16 acco0 = zero16(), acco1 = zero16();
  float mrow = -3e38f, lrowh = 0.f;

  // ---- prologue: V(0)->Vt[0]; V(1)->regs; K(0) gloads ----
  u16x8 va, vb;
  {
    const u16* vs = Vb + (size_t)(2 * kp) * 64 + do8 * 8;
    va = *(const u16x8*)vs; vb = *(const u16x8*)(vs + 64);
  }
#pragma unroll
  for (int i = 0; i < 8; ++i)
    Vt[0][voff[i]] = (unsigned)va[i] | ((unsigned)vb[i] << 16);
  {
    const u16* vs = Vb + (size_t)(64 + 2 * kp) * 64 + do8 * 8;
    va = *(const u16x8*)vs; vb = *(const u16x8*)(vs + 64);
  }
#pragma unroll
  for (int rep = 0; rep < 2; ++rep) {
    const int key = wave * 16 + rep * 8 + kkey8;
    gload_lds16(Kb + (size_t)key * 64 + (ksl ^ (key & 7)) * 8,
                &Ks[0][(wave * 2 + rep) * 512]);
  }

  for (int t = 0; t < ntiles; ++t) {
    const int kv0 = t * 64;
    __syncthreads();  // drains K(t) gloads; syncs V(t) stores; prev reads done

    if (t + 1 < ntiles) {
      const int nb = (t + 1) & 1;
#pragma unroll
      for (int i = 0; i < 8; ++i)
        Vt[nb][voff[i]] = (unsigned)va[i] | ((unsigned)vb[i] << 16);
#pragma unroll
      for (int rep = 0; rep < 2; ++rep) {
        const int key = wave * 16 + rep * 8 + kkey8;
        gload_lds16(Kb + (size_t)(kv0 + 64 + key) * 64 + (ksl ^ (key & 7)) * 8,
                    &Ks[nb][(wave * 2 + rep) * 512]);
      }
      if (t + 2 < ntiles) {
        const u16* vs = Vb + (size_t)(kv0 + 128 + 2 * kp) * 64 + do8 * 8;
        va = *(const u16x8*)vs; vb = *(const u16x8*)(vs + 64);
      }
    }

    if (kv0 > qstart + 31) continue;  // wave-uniform skip (barrier already done)

    const u16* Ksb = &Ks[t & 1][0];
    const unsigned* Vtb = &Vt[t & 1][0];
    const int qv = qstart + l31;
    const bool pres1 = (kv0 + 32 <= qstart + 31);

    // ---- QK^T ----
    f32x16 st0 = zero16(), st1 = zero16();
    __builtin_amdgcn_s_setprio(1);
#pragma unroll
    for (int ds = 0; ds < 4; ++ds) {
      const int sl = (((ds << 1) | hi) ^ (l31 & 7)) * 8;
      bf16x8 ak0 = *(const bf16x8*)&Ksb[l31 * 64 + sl];
      st0 = MFMA32(ak0, bq[ds], st0);
      if (pres1) {
        bf16x8 ak1 = *(const bf16x8*)&Ksb[(32 + l31) * 64 + sl];
        st1 = MFMA32(ak1, bq[ds], st1);
      }
    }
    __builtin_amdgcn_s_setprio(0);

    // ---- mask into st, local max ----
    float tl = -3e38f;
    if (kv0 + 31 > qstart) {
      const int kb0 = kv0 + 4 * hi;
#pragma unroll
      for (int r = 0; r < 16; ++r) {
        const int key = kb0 + (r & 3) + 8 * (r >> 2);
        float v = st0[r];
        v = (key <= qv) ? v : -3e38f;
        st0[r] = v;
        tl = fmaxf(tl, v);
      }
    } else {
#pragma unroll
      for (int r = 0; r < 16; ++r) tl = fmaxf(tl, st0[r]);
    }
    if (pres1) {
      if (kv0 + 63 > qstart) {
        const int kb1 = kv0 + 32 + 4 * hi;
#pragma unroll
        for (int r = 0; r < 16; ++r) {
          const int key = kb1 + (r & 3) + 8 * (r >> 2);
          float v = st1[r];
          v = (key <= qv) ? v : -3e38f;
          st1[r] = v;
          tl = fmaxf(tl, v);
        }
      } else {
#pragma unroll
        for (int r = 0; r < 16; ++r) tl = fmaxf(tl, st1[r]);
      }
    }

    // ---- defer-max decision ----
    float mn;
    if (__all(tl <= mrow + 8.0f)) {
      mn = mrow;                      // deferred: no shfl, no rescale
    } else {
      const float tj = fmaxf(tl, __shfl_xor(tl, 32, 64));
      mn = fmaxf(mrow, tj);
      const float al = exp2f(mrow - mn);
      mrow = mn;
      lrowh *= al;
#pragma unroll
      for (int r = 0; r < 16; ++r) { acco0[r] *= al; acco1[r] *= al; }
    }

    // ---- chunk 0 (keys kv0 .. kv0+31): exp in place, sum, pack, PV ----
    {
#pragma unroll
      for (int r = 0; r < 16; ++r) st0[r] = exp2f(st0[r] - mn);
      const float t0 = (st0[0] + st0[1]) + (st0[2] + st0[3]);
      const float t1 = (st0[4] + st0[5]) + (st0[6] + st0[7]);
      const float t2 = (st0[8] + st0[9]) + (st0[10] + st0[11]);
      const float t3 = (st0[12] + st0[13]) + (st0[14] + st0[15]);
      lrowh += (t0 + t1) + (t2 + t3);
      U4 f0, f1;
      packP(st0, hi, f0, f1);
      __builtin_amdgcn_s_setprio(1);
      {
        const int dbase = l31 * 32, sz = swzA;
        const bf16x8 vfa = *(const bf16x8*)&Vtb[dbase + ((hi * 4) ^ sz)];
        acco0 = MFMA32(vfa, f0.v, acco0);
        const bf16x8 vfb = *(const bf16x8*)&Vtb[dbase + ((8 + hi * 4) ^ sz)];
        acco0 = MFMA32(vfb, f1.v, acco0);
      }
      {
        const int dbase = (32 + l31) * 32, sz = swzA ^ 16;
        const bf16x8 vfa = *(const bf16x8*)&Vtb[dbase + ((hi * 4) ^ sz)];
        acco1 = MFMA32(vfa, f0.v, acco1);
        const bf16x8 vfb = *(const bf16x8*)&Vtb[dbase + ((8 + hi * 4) ^ sz)];
        acco1 = MFMA32(vfb, f1.v, acco1);
      }
      __builtin_amdgcn_s_setprio(0);
    }
    // ---- chunk 1 (keys kv0+32 .. kv0+63) ----
    if (pres1) {
#pragma unroll
      for (int r = 0; r < 16; ++r) st1[r] = exp2f(st1[r] - mn);
      const float t0 = (st1[0] + st1[1]) + (st1[2] + st1[3]);
      const float t1 = (st1[4] + st1[5]) + (st1[6] + st1[7]);
      const float t2 = (st1[8] + st1[9]) + (st1[10] + st1[11]);
      const float t3 = (st1[12] + st1[13]) + (st1[14] + st1[15]);
      lrowh += (t0 + t1) + (t2 + t3);
      U4 f0, f1;
      packP(st1, hi, f0, f1);
      __builtin_amdgcn_s_setprio(1);
      {
        const int dbase = l31 * 32, sz = swzA;
        const bf16x8 vfa = *(const bf16x8*)&Vtb[dbase + ((16 + hi * 4) ^ sz)];
        acco0 = MFMA32(vfa, f0.v, acco0);
        const bf16x8 vfb = *(const bf16x8*)&Vtb[dbase + ((24 + hi * 4) ^ sz)];
        acco0 = MFMA32(vfb, f1.v, acco0);
      }
      {
        const int dbase = (32 + l31) * 32, sz = swzA ^ 16;
        const bf16x8 vfa = *(const bf16x8*)&Vtb[dbase + ((16 + hi * 4) ^ sz)];
        acco1 = MFMA32(vfa, f0.v, acco1);
        const bf16x8 vfb = *(const bf16x8*)&Vtb[dbase + ((24 + hi * 4) ^ sz)];
        acco1 = MFMA32(vfb, f1.v, acco1);
      }
      __builtin_amdgcn_s_setprio(0);
    }
  }

  // ---- epilogue: merge l across halves once; write O^T rows ----
  const float lrow = lrowh + __shfl_xor(lrowh, 32, 64);
  const float rl = 1.0f / lrow;
  u16* orow = ctx + ((size_t)bb * kS + (qstart + l31)) * kD + hh * 64;
#pragma unroll
  for (int rq = 0; rq < 4; ++rq) {
    u16x4 pk0, pk1;
#pragma unroll
    for (int c = 0; c < 4; ++c) {
      pk0[c] = f2bf(acco0[rq * 4 + c] * rl);
      pk1[c] = f2bf(acco1[rq * 4 + c] * rl);
    }
    *(u16x4*)&orow[rq * 8 + hi * 4] = pk0;
    *(u16x4*)&orow[32 + rq * 8 + hi * 4] = pk1;
  }
}

// ---------------- launcher ----------------
extern "C" void kernel_launch(void* const* d_in, const int* in_sizes, int n_in,
                              void* d_out, int out_size, void* d_ws, size_t ws_size,
                              hipStream_t stream) {
  const float* x     = (const float*)d_in[0];
  const float* w_qkv = (const float*)d_in[1];
  const float* w_out = (const float*)d_in[2];
  float* out = (float*)d_out;

  u16* ws    = (u16*)d_ws;
  u16* x_bf  = ws;                                  // 8192*1024
  u16* wqkvT = x_bf + (size_t)M1 * K1;              // 3072*1024
  u16* woutT = wqkvT + (size_t)N1 * K1;             // 1024*1024
  u16* qkv   = woutT + (size_t)kD * kD;             // 3 * 64*2048*64
  u16* ctx   = qkv + (size_t)3 * kB * kH * kS * kHD;  // 8192*1024

  k_cast_x<<<M1 * K1 / 1024, 256, 0, stream>>>(x, x_bf);
  k_transpose_cast<<<dim3(N1 / 32, K1 / 32), 256, 0, stream>>>(w_qkv, wqkvT, K1, N1);
  k_transpose_cast<<<dim3(kD / 32, kD / 32), 256, 0, stream>>>(w_out, woutT, kD, kD);

  k_gemm_bt<0><<<dim3(N1 / 128, M1 / 128), 256, 0, stream>>>(x_bf, wqkvT, qkv, nullptr,
                                                             M1, N1, K1);

  const u16* Qg = qkv;
  const u16* Kg = qkv + (size_t)kB * kH * kS * kHD;
  const u16* Vg = qkv + (size_t)2 * kB * kH * kS * kHD;
  k_attn<<<dim3(1024), 256, 0, stream>>>(Qg, Kg, Vg, ctx);

  k_gemm_bt<1><<<dim3(kD / 128, M1 / 128), 256, 0, stream>>>(ctx, woutT, nullptr, out,
                                                             M1, kD, K1);
}

// Round 8
// 214.958 us; speedup vs baseline: 1.6330x; 1.1754x over previous
//
#include <hip/hip_runtime.h>
#include <stdint.h>

typedef unsigned short u16;
typedef __attribute__((ext_vector_type(4))) float f32x4;
typedef __attribute__((ext_vector_type(16))) float f32x16;
typedef __attribute__((ext_vector_type(8))) __bf16 bf16x8;
typedef __attribute__((ext_vector_type(8))) u16 u16x8;
typedef __attribute__((ext_vector_type(4))) u16 u16x4;

static constexpr int kB = 4, kS = 2048, kD = 1024, kH = 16, kHD = 64;
static constexpr int M1 = kB * kS;   // 8192
static constexpr int N1 = 3 * kD;    // 3072
static constexpr int K1 = kD;        // 1024

// 1/sqrt(64) * log2(e), folded into Q at GEMM1 epilogue
#define SCLF 0.18033688011112042f
#define MFMA32(a, b, c) __builtin_amdgcn_mfma_f32_32x32x16_bf16((a), (b), (c), 0, 0, 0)

union U4 { unsigned u[4]; bf16x8 v; };

__device__ __forceinline__ u16 f2bf(float f) {
  union { float f; uint32_t u; } c; c.f = f;
  uint32_t u = c.u + 0x7FFFu + ((c.u >> 16) & 1u);   // RNE
  return (u16)(u >> 16);
}

__device__ __forceinline__ unsigned pkbf(float a, float b) {
  union { __bf16 h[2]; unsigned u; } c;
  c.h[0] = (__bf16)a; c.h[1] = (__bf16)b;
  return c.u;
}

__device__ __forceinline__ f32x16 zero16() {
  f32x16 v;
#pragma unroll
  for (int i = 0; i < 16; ++i) v[i] = 0.f;
  return v;
}

__device__ __forceinline__ void gload_lds16(const u16* g, u16* l) {
  __builtin_amdgcn_global_load_lds(
      (const __attribute__((address_space(1))) unsigned int*)g,
      (__attribute__((address_space(3))) unsigned int*)l, 16, 0, 0);
}

// P redistribution: p[16] (C-layout rows, already exp'd) -> two B-frags
__device__ __forceinline__ void packP(const f32x16& pp, int hi, U4& f0, U4& f1) {
  const unsigned qa0 = pkbf(pp[0], pp[1]),   qa1 = pkbf(pp[2], pp[3]);
  const unsigned qb0 = pkbf(pp[4], pp[5]),   qb1 = pkbf(pp[6], pp[7]);
  const unsigned qc0 = pkbf(pp[8], pp[9]),   qc1 = pkbf(pp[10], pp[11]);
  const unsigned qd0 = pkbf(pp[12], pp[13]), qd1 = pkbf(pp[14], pp[15]);
  const unsigned xa0 = __shfl_xor(qa0, 32, 64), xa1 = __shfl_xor(qa1, 32, 64);
  const unsigned xb0 = __shfl_xor(qb0, 32, 64), xb1 = __shfl_xor(qb1, 32, 64);
  const unsigned xc0 = __shfl_xor(qc0, 32, 64), xc1 = __shfl_xor(qc1, 32, 64);
  const unsigned xd0 = __shfl_xor(qd0, 32, 64), xd1 = __shfl_xor(qd1, 32, 64);
  f0.u[0] = hi ? xb0 : qa0; f0.u[1] = hi ? xb1 : qa1;
  f0.u[2] = hi ? qb0 : xa0; f0.u[3] = hi ? qb1 : xa1;
  f1.u[0] = hi ? xd0 : qc0; f1.u[1] = hi ? xd1 : qc1;
  f1.u[2] = hi ? qd0 : xc0; f1.u[3] = hi ? qd1 : xc1;
}

// ---------------- cast kernels ----------------
__global__ __launch_bounds__(256) void k_cast_x(const float* __restrict__ x,
                                                u16* __restrict__ o) {
  int i = (blockIdx.x * 256 + threadIdx.x) * 4;
  f32x4 v = *(const f32x4*)(x + i);
  u16x4 r;
  r[0] = f2bf(v[0]); r[1] = f2bf(v[1]); r[2] = f2bf(v[2]); r[3] = f2bf(v[3]);
  *(u16x4*)(o + i) = r;
}

// w: [K][N] f32  ->  wt: [N][K] bf16   (B^T layout for GEMM)
__global__ __launch_bounds__(256) void k_transpose_cast(const float* __restrict__ w,
                                                        u16* __restrict__ wt,
                                                        int K, int N) {
  __shared__ float t[32][33];
  const int n0 = blockIdx.x * 32, k0 = blockIdx.y * 32;
  const int tx = threadIdx.x & 31, ty = threadIdx.x >> 5;
  for (int r = ty; r < 32; r += 8)
    t[r][tx] = w[(size_t)(k0 + r) * N + n0 + tx];
  __syncthreads();
  for (int r = ty; r < 32; r += 8)
    wt[(size_t)(n0 + r) * K + k0 + tx] = f2bf(t[tx][r]);
}

// ---------------- GEMM (A row-major MxK, BT row-major NxK) ----------------
// XCD swizzle: contiguous tile chunk per XCD (nwg % 8 == 0 for all our grids)
template <int MODE>
__global__ __launch_bounds__(256) void k_gemm_bt(const u16* __restrict__ A,
                                                 const u16* __restrict__ BT,
                                                 u16* __restrict__ obf,
                                                 float* __restrict__ of,
                                                 int M, int N, int K) {
  typedef __attribute__((ext_vector_type(4))) float f4;
  __shared__ __align__(16) u16 As[128 * 32];
  __shared__ __align__(16) u16 Bs[128 * 32];
  const int tid = threadIdx.x;
  const int wave = tid >> 6, lane = tid & 63;
  const int l15 = lane & 15, l16 = lane >> 4;

  const int bid = blockIdx.y * gridDim.x + blockIdx.x;
  const int qch = (gridDim.x * gridDim.y) >> 3;
  const int swz = (bid & 7) * qch + (bid >> 3);
  const int row0 = (swz / gridDim.x) * 128, col0 = (swz % gridDim.x) * 128;
  const int wm = (wave >> 1) * 64, wn = (wave & 1) * 64;

  f4 acc[4][4];
#pragma unroll
  for (int i = 0; i < 4; ++i)
#pragma unroll
    for (int j = 0; j < 4; ++j) acc[i][j] = f4{0.f, 0.f, 0.f, 0.f};

  const int e0 = wave * 512 + lane * 8;
  const int r0 = e0 >> 5, c0 = e0 & 31;
  const int e1 = e0 + 2048;
  const int r1 = e1 >> 5, c1 = e1 & 31;
  const u16* Ab = A + (size_t)row0 * K;
  const u16* Bb = BT + (size_t)col0 * K;

  for (int kt = 0; kt < K; kt += 32) {
    gload_lds16(Ab + (size_t)r0 * K + kt + c0, &As[wave * 512]);
    gload_lds16(Ab + (size_t)r1 * K + kt + c1, &As[2048 + wave * 512]);
    gload_lds16(Bb + (size_t)r0 * K + kt + c0, &Bs[wave * 512]);
    gload_lds16(Bb + (size_t)r1 * K + kt + c1, &Bs[2048 + wave * 512]);
    __syncthreads();
    bf16x8 af[4], bfv[4];
#pragma unroll
    for (int f = 0; f < 4; ++f) {
      af[f]  = *(const bf16x8*)&As[(wm + f * 16 + l15) * 32 + l16 * 8];
      bfv[f] = *(const bf16x8*)&Bs[(wn + f * 16 + l15) * 32 + l16 * 8];
    }
#pragma unroll
    for (int fm = 0; fm < 4; ++fm)
#pragma unroll
      for (int fn = 0; fn < 4; ++fn)
        acc[fm][fn] = __builtin_amdgcn_mfma_f32_16x16x32_bf16(af[fm], bfv[fn],
                                                              acc[fm][fn], 0, 0, 0);
    __syncthreads();
  }

#pragma unroll
  for (int fm = 0; fm < 4; ++fm)
#pragma unroll
    for (int fn = 0; fn < 4; ++fn) {
      const int n = col0 + wn + fn * 16 + l15;
#pragma unroll
      for (int j = 0; j < 4; ++j) {
        const int m = row0 + wm + fm * 16 + l16 * 4 + j;
        float v = acc[fm][fn][j];
        if constexpr (MODE == 0) {
          const int which = n >> 10, d = n & 1023;
          const int h = d >> 6, hd = d & 63;
          const int b = m >> 11, s = m & 2047;
          if (which == 0) v *= SCLF;   // fold softmax scale (log2 dom) into Q
          obf[((((size_t)which * 4 + b) * 16 + h) * 2048 + s) * 64 + hd] = f2bf(v);
        } else {
          of[(size_t)m * N + n] = v;
        }
      }
    }
}

// ---------------- flash attention v8 (split-KV, 8 waves, paired, 32-chunks) ----
// grid: 512 blocks x 512 threads. Decode: xcd=bid&7, bh=xcd*8+(i2&7), p=i2>>3.
// Block does q-superblocks {p, 15-p} sequentially (uniform 34 tiles); within a
// phase, group g = wave>>2 processes KV tiles t=2i+g (even/odd split, 17 each);
// groups merged per phase via LDS flash-combine (a_g = 2^(m_g-m*)).
// Keys processed in 32-chunks to halve st AGPRs -> ~123 total regs, fits
// __launch_bounds__(512,4) (cap 128) for 2 blocks/CU = 16 waves/CU.
// Verify: WRITE_SIZE must stay ~16.4MB (ctx only); growth = spill = revert cap.
__global__ __launch_bounds__(512, 4) void k_attn(const u16* __restrict__ Qg,
                                                 const u16* __restrict__ Kg,
                                                 const u16* __restrict__ Vg,
                                                 u16* __restrict__ ctx) {
  // 64KB: [0..16383] u16: K, 2 groups x 2 bufs x 4096; [16384..]: V^T as u32,
  // 2 groups x 2 bufs x 2048. Reused as merge scratch between phases.
  __shared__ __align__(16) u16 SMEM[32768];

  const int bid = blockIdx.x;
  const int xcd = bid & 7, i2 = bid >> 3;
  const int bh = xcd * 8 + (i2 & 7);
  const int p = i2 >> 3;                      // 0..7
  const int bb = bh >> 4, hh = bh & 15;
  const int tid = threadIdx.x;
  const int wave = tid >> 6, lane = tid & 63;
  const int g = wave >> 2, w4 = wave & 3;
  const int l31 = lane & 31, hi = lane >> 5;

  const u16* Qb = Qg + (size_t)bh * kS * kHD;
  const u16* Kb = Kg + (size_t)bh * kS * kHD;
  const u16* Vb = Vg + (size_t)bh * kS * kHD;

  u16* Ksg = SMEM + g * 8192;                            // 2 bufs x 4096 u16
  unsigned* Vtg = (unsigned*)(SMEM + 16384) + g * 4096;  // 2 bufs x 2048 u32

  const int tidg = tid & 255;
  const int do8 = tidg & 7, kp = tidg >> 3;      // V staging: d-slice, key-pair
  const int kkey8 = lane >> 3, ksl = lane & 7;   // K staging lane map
  const int swzA = (((l31 & 7) ^ (l31 >> 3)) << 2);

  // per-thread V LDS store offsets (constant across tiles)
  unsigned voff[8];
#pragma unroll
  for (int i = 0; i < 8; ++i) {
    const int d = do8 * 8 + i;
    voff[i] = d * 32 + (kp ^ ((((d & 7) ^ (d >> 3))) << 2));
  }

  for (int phase = 0; phase < 2; ++phase) {
    const int qsup = phase ? (15 - p) : p;
    const int s0 = qsup * 128;
    const int qstart = s0 + w4 * 32;
    const int nIter = qsup + 1;        // per-group iterations (64-key tiles)

    // Q B-frags: row q = qstart + l31, k = ds*16 + hi*8 + i
    bf16x8 bq[4];
#pragma unroll
    for (int ds = 0; ds < 4; ++ds)
      bq[ds] = *(const bf16x8*)(Qb + (size_t)(qstart + l31) * 64 + ds * 16 + hi * 8);

    f32x16 acco0 = zero16(), acco1 = zero16();
    float mrow = -3e38f, lrowh = 0.f;

    // protect SMEM: previous phase's merge readers must be done
    __syncthreads();

    // ---- prologue: stage tile g (buf0); preload V regs for tile 2+g ----
    u16x8 va, vb;
    {
      const u16* vs = Vb + (size_t)(g * 64 + 2 * kp) * 64 + do8 * 8;
      va = *(const u16x8*)vs; vb = *(const u16x8*)(vs + 64);
    }
#pragma unroll
    for (int i = 0; i < 8; ++i)
      Vtg[voff[i]] = (unsigned)va[i] | ((unsigned)vb[i] << 16);
    {
      const u16* vs = Vb + (size_t)((2 + g) * 64 + 2 * kp) * 64 + do8 * 8;
      va = *(const u16x8*)vs; vb = *(const u16x8*)(vs + 64);
    }
#pragma unroll
    for (int rep = 0; rep < 2; ++rep) {
      const int key = w4 * 16 + rep * 8 + kkey8;
      gload_lds16(Kb + (size_t)(g * 64 + key) * 64 + (ksl ^ (key & 7)) * 8,
                  &Ksg[(w4 * 2 + rep) * 512]);
    }

    for (int i = 0; i < nIter; ++i) {
      const int kv0 = (2 * i + g) * 64;
      __syncthreads();  // drains this buf's K gloads; syncs V stores; prev reads done

      if (i + 1 < nIter) {
        const int nb = (i + 1) & 1;
#pragma unroll
        for (int r = 0; r < 8; ++r)
          Vtg[nb * 2048 + voff[r]] = (unsigned)va[r] | ((unsigned)vb[r] << 16);
        const int nt = 2 * (i + 1) + g;
#pragma unroll
        for (int rep = 0; rep < 2; ++rep) {
          const int key = w4 * 16 + rep * 8 + kkey8;
          gload_lds16(Kb + (size_t)(nt * 64 + key) * 64 + (ksl ^ (key & 7)) * 8,
                      &Ksg[nb * 4096 + (w4 * 2 + rep) * 512]);
        }
        if (i + 2 < nIter) {
          const u16* vs = Vb + (size_t)((2 * (i + 2) + g) * 64 + 2 * kp) * 64 + do8 * 8;
          va = *(const u16x8*)vs; vb = *(const u16x8*)(vs + 64);
        }
      }

      if (kv0 > qstart + 31) continue;  // wave-uniform skip (barrier already done)

      const u16* Ksb = &Ksg[(i & 1) * 4096];
      const unsigned* Vtb = &Vtg[(i & 1) * 2048];
      const int qv = qstart + l31;

#pragma unroll
      for (int c = 0; c < 2; ++c) {
        const int kb = kv0 + 32 * c;
        if (kb > qstart + 31) continue;  // chunk fully masked (wave-uniform)

        // ---- QK^T (32 keys) ----
        f32x16 st = zero16();
        __builtin_amdgcn_s_setprio(1);
#pragma unroll
        for (int ds = 0; ds < 4; ++ds) {
          const int sl = (((ds << 1) | hi) ^ (l31 & 7)) * 8;
          bf16x8 ak = *(const bf16x8*)&Ksb[(32 * c + l31) * 64 + sl];
          st = MFMA32(ak, bq[ds], st);
        }
        __builtin_amdgcn_s_setprio(0);

        // ---- mask + local max ----
        float tl = -3e38f;
        if (kb + 31 > qstart) {
          const int kb0 = kb + 4 * hi;
#pragma unroll
          for (int r = 0; r < 16; ++r) {
            const int key = kb0 + (r & 3) + 8 * (r >> 2);
            float v = st[r];
            v = (key <= qv) ? v : -3e38f;
            st[r] = v;
            tl = fmaxf(tl, v);
          }
        } else {
#pragma unroll
          for (int r = 0; r < 16; ++r) tl = fmaxf(tl, st[r]);
        }

        // ---- defer-max ----
        float mn;
        if (__all(tl <= mrow + 8.0f)) {
          mn = mrow;
        } else {
          const float tj = fmaxf(tl, __shfl_xor(tl, 32, 64));
          mn = fmaxf(mrow, tj);
          const float al = exp2f(mrow - mn);
          mrow = mn;
          lrowh *= al;
#pragma unroll
          for (int r = 0; r < 16; ++r) { acco0[r] *= al; acco1[r] *= al; }
        }

        // ---- exp in place, sum, pack, PV ----
#pragma unroll
        for (int r = 0; r < 16; ++r) st[r] = exp2f(st[r] - mn);
        {
          const float t0 = (st[0] + st[1]) + (st[2] + st[3]);
          const float t1 = (st[4] + st[5]) + (st[6] + st[7]);
          const float t2 = (st[8] + st[9]) + (st[10] + st[11]);
          const float t3 = (st[12] + st[13]) + (st[14] + st[15]);
          lrowh += (t0 + t1) + (t2 + t3);
        }
        U4 f0, f1;
        packP(st, hi, f0, f1);
        __builtin_amdgcn_s_setprio(1);
        {
          const int dbase = l31 * 32, sz = swzA;
          const bf16x8 vfa = *(const bf16x8*)&Vtb[dbase + ((16 * c + hi * 4) ^ sz)];
          acco0 = MFMA32(vfa, f0.v, acco0);
          const bf16x8 vfb = *(const bf16x8*)&Vtb[dbase + ((16 * c + 8 + hi * 4) ^ sz)];
          acco0 = MFMA32(vfb, f1.v, acco0);
        }
        {
          const int dbase = (32 + l31) * 32, sz = swzA ^ 16;
          const bf16x8 vfa = *(const bf16x8*)&Vtb[dbase + ((16 * c + hi * 4) ^ sz)];
          acco1 = MFMA32(vfa, f0.v, acco1);
          const bf16x8 vfb = *(const bf16x8*)&Vtb[dbase + ((16 * c + 8 + hi * 4) ^ sz)];
          acco1 = MFMA32(vfb, f1.v, acco1);
        }
        __builtin_amdgcn_s_setprio(0);
      }
    }

    // ---- per-phase group merge (flash combine) + writeout by group 0 ----
    __syncthreads();  // all compute done; SMEM reusable as scratch
    const float lfull = lrowh + __shfl_xor(lrowh, 32, 64);
    float* sc1 = (float*)SMEM;             // 8192 floats: acco (32/lane)
    float* sc2 = (float*)(SMEM + 16384);   // meta: m, l per lane
    const int mbase = (w4 * 64 + lane) * 32;
    const int meta = (w4 * 64 + lane) * 2;
    if (g == 1) {
#pragma unroll
      for (int r = 0; r < 16; ++r) {
        sc1[mbase + (r ^ l31)] = acco0[r];
        sc1[mbase + ((16 + r) ^ l31)] = acco1[r];
      }
      sc2[meta] = mrow;
      sc2[meta + 1] = lfull;
    }
    __syncthreads();
    if (g == 0) {
      const float m1 = sc2[meta], l1 = sc2[meta + 1];
      const float mM = fmaxf(mrow, m1);
      const float a0 = exp2f(mrow - mM), a1 = exp2f(m1 - mM);
      const float rl = 1.0f / (a0 * lfull + a1 * l1);
      u16* orow = ctx + ((size_t)bb * kS + (qstart + l31)) * kD + hh * 64;
#pragma unroll
      for (int rq = 0; rq < 4; ++rq) {
        u16x4 pk0, pk1;
#pragma unroll
        for (int c = 0; c < 4; ++c) {
          const int r = rq * 4 + c;
          pk0[c] = f2bf((a0 * acco0[r] + a1 * sc1[mbase + (r ^ l31)]) * rl);
          pk1[c] = f2bf((a0 * acco1[r] + a1 * sc1[mbase + ((16 + r) ^ l31)]) * rl);
        }
        *(u16x4*)&orow[rq * 8 + hi * 4] = pk0;
        *(u16x4*)&orow[32 + rq * 8 + hi * 4] = pk1;
      }
    }
  }
}

// ---------------- launcher ----------------
extern "C" void kernel_launch(void* const* d_in, const int* in_sizes, int n_in,
                              void* d_out, int out_size, void* d_ws, size_t ws_size,
                              hipStream_t stream) {
  const float* x     = (const float*)d_in[0];
  const float* w_qkv = (const float*)d_in[1];
  const float* w_out = (const float*)d_in[2];
  float* out = (float*)d_out;

  u16* ws    = (u16*)d_ws;
  u16* x_bf  = ws;                                  // 8192*1024
  u16* wqkvT = x_bf + (size_t)M1 * K1;              // 3072*1024
  u16* woutT = wqkvT + (size_t)N1 * K1;             // 1024*1024
  u16* qkv   = woutT + (size_t)kD * kD;             // 3 * 64*2048*64
  u16* ctx   = qkv + (size_t)3 * kB * kH * kS * kHD;  // 8192*1024

  k_cast_x<<<M1 * K1 / 1024, 256, 0, stream>>>(x, x_bf);
  k_transpose_cast<<<dim3(N1 / 32, K1 / 32), 256, 0, stream>>>(w_qkv, wqkvT, K1, N1);
  k_transpose_cast<<<dim3(kD / 32, kD / 32), 256, 0, stream>>>(w_out, woutT, kD, kD);

  k_gemm_bt<0><<<dim3(N1 / 128, M1 / 128), 256, 0, stream>>>(x_bf, wqkvT, qkv, nullptr,
                                                             M1, N1, K1);

  const u16* Qg = qkv;
  const u16* Kg = qkv + (size_t)kB * kH * kS * kHD;
  const u16* Vg = qkv + (size_t)2 * kB * kH * kS * kHD;
  k_attn<<<dim3(512), 512, 0, stream>>>(Qg, Kg, Vg, ctx);

  k_gemm_bt<1><<<dim3(kD / 128, M1 / 128), 256, 0, stream>>>(ctx, woutT, nullptr, out,
                                                             M1, kD, K1);
}

// Round 9
// 206.079 us; speedup vs baseline: 1.7034x; 1.0431x over previous
//
#include <hip/hip_runtime.h>
#include <stdint.h>

typedef unsigned short u16;
typedef __attribute__((ext_vector_type(4))) float f32x4;
typedef __attribute__((ext_vector_type(8))) __bf16 bf16x8;
typedef __attribute__((ext_vector_type(8))) u16 u16x8;
typedef __attribute__((ext_vector_type(4))) u16 u16x4;

static constexpr int kB = 4, kS = 2048, kD = 1024, kH = 16, kHD = 64;
static constexpr int M1 = kB * kS;   // 8192
static constexpr int N1 = 3 * kD;    // 3072
static constexpr int K1 = kD;        // 1024

// 1/sqrt(64) * log2(e), folded into Q at GEMM1 epilogue
#define SCLF 0.18033688011112042f
#define MFMA16(a, b, c) __builtin_amdgcn_mfma_f32_16x16x32_bf16((a), (b), (c), 0, 0, 0)

union U4 { unsigned u[4]; bf16x8 v; };

__device__ __forceinline__ u16 f2bf(float f) {
  union { float f; uint32_t u; } c; c.f = f;
  uint32_t u = c.u + 0x7FFFu + ((c.u >> 16) & 1u);   // RNE
  return (u16)(u >> 16);
}

__device__ __forceinline__ unsigned pkbf(float a, float b) {
  union { __bf16 h[2]; unsigned u; } c;
  c.h[0] = (__bf16)a; c.h[1] = (__bf16)b;
  return c.u;
}

__device__ __forceinline__ void gload_lds16(const u16* g, u16* l) {
  __builtin_amdgcn_global_load_lds(
      (const __attribute__((address_space(1))) unsigned int*)g,
      (__attribute__((address_space(3))) unsigned int*)l, 16, 0, 0);
}

// ---------------- cast kernels ----------------
__global__ __launch_bounds__(256) void k_cast_x(const float* __restrict__ x,
                                                u16* __restrict__ o) {
  int i = (blockIdx.x * 256 + threadIdx.x) * 4;
  f32x4 v = *(const f32x4*)(x + i);
  u16x4 r;
  r[0] = f2bf(v[0]); r[1] = f2bf(v[1]); r[2] = f2bf(v[2]); r[3] = f2bf(v[3]);
  *(u16x4*)(o + i) = r;
}

// w: [K][N] f32  ->  wt: [N][K] bf16   (B^T layout for GEMM)
__global__ __launch_bounds__(256) void k_transpose_cast(const float* __restrict__ w,
                                                        u16* __restrict__ wt,
                                                        int K, int N) {
  __shared__ float t[32][33];
  const int n0 = blockIdx.x * 32, k0 = blockIdx.y * 32;
  const int tx = threadIdx.x & 31, ty = threadIdx.x >> 5;
  for (int r = ty; r < 32; r += 8)
    t[r][tx] = w[(size_t)(k0 + r) * N + n0 + tx];
  __syncthreads();
  for (int r = ty; r < 32; r += 8)
    wt[(size_t)(n0 + r) * K + k0 + tx] = f2bf(t[tx][r]);
}

// ---------------- GEMM (A row-major MxK, BT row-major NxK) ----------------
// XCD swizzle: contiguous tile chunk per XCD (nwg % 8 == 0 for all our grids)
template <int MODE>
__global__ __launch_bounds__(256) void k_gemm_bt(const u16* __restrict__ A,
                                                 const u16* __restrict__ BT,
                                                 u16* __restrict__ obf,
                                                 float* __restrict__ of,
                                                 int M, int N, int K) {
  typedef __attribute__((ext_vector_type(4))) float f4;
  __shared__ __align__(16) u16 As[128 * 32];
  __shared__ __align__(16) u16 Bs[128 * 32];
  const int tid = threadIdx.x;
  const int wave = tid >> 6, lane = tid & 63;
  const int l15 = lane & 15, l16 = lane >> 4;

  const int bid = blockIdx.y * gridDim.x + blockIdx.x;
  const int qch = (gridDim.x * gridDim.y) >> 3;
  const int swz = (bid & 7) * qch + (bid >> 3);
  const int row0 = (swz / gridDim.x) * 128, col0 = (swz % gridDim.x) * 128;
  const int wm = (wave >> 1) * 64, wn = (wave & 1) * 64;

  f4 acc[4][4];
#pragma unroll
  for (int i = 0; i < 4; ++i)
#pragma unroll
    for (int j = 0; j < 4; ++j) acc[i][j] = f4{0.f, 0.f, 0.f, 0.f};

  const int e0 = wave * 512 + lane * 8;
  const int r0 = e0 >> 5, c0 = e0 & 31;
  const int e1 = e0 + 2048;
  const int r1 = e1 >> 5, c1 = e1 & 31;
  const u16* Ab = A + (size_t)row0 * K;
  const u16* Bb = BT + (size_t)col0 * K;

  for (int kt = 0; kt < K; kt += 32) {
    gload_lds16(Ab + (size_t)r0 * K + kt + c0, &As[wave * 512]);
    gload_lds16(Ab + (size_t)r1 * K + kt + c1, &As[2048 + wave * 512]);
    gload_lds16(Bb + (size_t)r0 * K + kt + c0, &Bs[wave * 512]);
    gload_lds16(Bb + (size_t)r1 * K + kt + c1, &Bs[2048 + wave * 512]);
    __syncthreads();
    bf16x8 af[4], bfv[4];
#pragma unroll
    for (int f = 0; f < 4; ++f) {
      af[f]  = *(const bf16x8*)&As[(wm + f * 16 + l15) * 32 + l16 * 8];
      bfv[f] = *(const bf16x8*)&Bs[(wn + f * 16 + l15) * 32 + l16 * 8];
    }
#pragma unroll
    for (int fm = 0; fm < 4; ++fm)
#pragma unroll
      for (int fn = 0; fn < 4; ++fn)
        acc[fm][fn] = MFMA16(af[fm], bfv[fn], acc[fm][fn]);
    __syncthreads();
  }

#pragma unroll
  for (int fm = 0; fm < 4; ++fm)
#pragma unroll
    for (int fn = 0; fn < 4; ++fn) {
      const int n = col0 + wn + fn * 16 + l15;
#pragma unroll
      for (int j = 0; j < 4; ++j) {
        const int m = row0 + wm + fm * 16 + l16 * 4 + j;
        float v = acc[fm][fn][j];
        if constexpr (MODE == 0) {
          const int which = n >> 10, d = n & 1023;
          const int h = d >> 6, hd = d & 63;
          const int b = m >> 11, s = m & 2047;
          if (which == 0) v *= SCLF;   // fold softmax scale (log2 dom) into Q
          obf[((((size_t)which * 4 + b) * 16 + h) * 2048 + s) * 64 + hd] = f2bf(v);
        } else {
          of[(size_t)m * N + n] = v;
        }
      }
    }
}

// ---------------- flash attention v9 (8 waves x 16 q-rows, 16x16x32) ----------
// grid: 512 blocks x 512 threads. Decode: xcd=bid&7, i2=bid>>3, bh=xcd*8+(i2&7),
// p=i2>>3; block does q-superblocks {p, 15-p} (uniform 34 tiles). 8 waves share
// one K/V LDS double-buffer (no split-KV, no merge). Wave owns 16 q rows ->
// acc 16 + st 8 AGPR; total regs ~110 < 128 so __launch_bounds__(512,4) gives
// 2 blocks/CU = 4 waves/SIMD WITHOUT spill (R8 spilled 60MB at q=32/wave).
// Layouts (GEMM-verified): A/B-frag lane=l15, k=l16*8+i; C col=l15, row=l16*4+j.
// S^T = mfma(K, Q): lane col = q = qstart+l15. O^T = mfma(V^T, P): col = q.
__global__ __launch_bounds__(512, 4) void k_attn(const u16* __restrict__ Qg,
                                                 const u16* __restrict__ Kg,
                                                 const u16* __restrict__ Vg,
                                                 u16* __restrict__ ctx) {
  __shared__ __align__(16) u16 Ks[2][64 * 64];        // 16 KB
  __shared__ __align__(16) unsigned Vt[2][2048];      // 16 KB  [d][kp] packed

  const int bid = blockIdx.x;
  const int xcd = bid & 7, i2 = bid >> 3;
  const int bh = xcd * 8 + (i2 & 7);
  const int p = i2 >> 3;                      // 0..7
  const int bb = bh >> 4, hh = bh & 15;
  const int tid = threadIdx.x;
  const int wave = tid >> 6, lane = tid & 63;
  const int l15 = lane & 15, l16 = lane >> 4;

  const u16* Qb = Qg + (size_t)bh * kS * kHD;
  const u16* Kb = Kg + (size_t)bh * kS * kHD;
  const u16* Vb = Vg + (size_t)bh * kS * kHD;

  const int kkey = tid >> 3, ksl = tid & 7;      // K staging: key, slot
  const int do4 = tid & 15, kp = tid >> 4;       // V staging: d-quad, key-pair
  const int srcA = ((l16 & 1) << 5) + l15;       // P-pack pull lanes
  const int srcB = srcA + 16;
  const bool lo16 = (l16 < 2);

  // per-thread V LDS store offsets (constant across tiles)
  unsigned voff[4];
#pragma unroll
  for (int i = 0; i < 4; ++i) {
    const int d = do4 * 4 + i;
    voff[i] = d * 32 + (kp ^ ((((d & 7) ^ (d >> 3))) << 2));
  }
  // K staged pre-swizzled: LDS[key][s] = global granule s^(key&7)
  const u16* ksrc = Kb + (size_t)kkey * 64 + (ksl ^ (kkey & 7)) * 8;

  for (int phase = 0; phase < 2; ++phase) {
    const int qsup = phase ? (15 - p) : p;
    const int qstart = qsup * 128 + wave * 16;
    const int ntiles = 2 * qsup + 2;           // 64-key tiles

    // Q B-frags: row q = qstart + l15, d = ds*32 + l16*8 + i
    bf16x8 bq[2];
#pragma unroll
    for (int ds = 0; ds < 2; ++ds)
      bq[ds] = *(const bf16x8*)(Qb + (size_t)(qstart + l15) * 64 + ds * 32 + l16 * 8);

    f32x4 acc[4];
#pragma unroll
    for (int i = 0; i < 4; ++i) acc[i] = f32x4{0.f, 0.f, 0.f, 0.f};
    float mrow = -3e38f, lrowh = 0.f;

    // phase-transition guard: prev phase's readers must be done before
    // prologue overwrites buffer 0 (round-4 race lesson)
    __syncthreads();

    // ---- prologue: V(0)->Vt[0]; V(1)->regs; K(0) gload ----
    u16x4 va, vb;
    {
      const u16* vs = Vb + (size_t)(2 * kp) * 64 + do4 * 4;
      va = *(const u16x4*)vs; vb = *(const u16x4*)(vs + 64);
    }
#pragma unroll
    for (int i = 0; i < 4; ++i)
      Vt[0][voff[i]] = (unsigned)va[i] | ((unsigned)vb[i] << 16);
    {
      const u16* vs = Vb + (size_t)(64 + 2 * kp) * 64 + do4 * 4;
      va = *(const u16x4*)vs; vb = *(const u16x4*)(vs + 64);
    }
    gload_lds16(ksrc, &Ks[0][wave * 512]);

    for (int t = 0; t < ntiles; ++t) {
      const int kv0 = t * 64;
      __syncthreads();  // drains K(t) gload; syncs V(t) stores; prev reads done

      if (t + 1 < ntiles) {
        const int nb = (t + 1) & 1;
#pragma unroll
        for (int i = 0; i < 4; ++i)
          Vt[nb][voff[i]] = (unsigned)va[i] | ((unsigned)vb[i] << 16);
        gload_lds16(ksrc + (size_t)(t + 1) * 64 * 64, &Ks[nb][wave * 512]);
        if (t + 2 < ntiles) {
          const u16* vs = Vb + (size_t)((t + 2) * 64 + 2 * kp) * 64 + do4 * 4;
          va = *(const u16x4*)vs; vb = *(const u16x4*)(vs + 64);
        }
      }

      if (kv0 > qstart + 15) continue;  // wave-uniform skip (barrier done above)

      const u16* Ksb = &Ks[t & 1][0];
      const unsigned* Vtb = &Vt[t & 1][0];
      const int qv = qstart + l15;

#pragma unroll
      for (int c = 0; c < 2; ++c) {
        const int kb = kv0 + 32 * c;
        if (kb > qstart + 15) continue;  // chunk fully masked (wave-uniform)

        // ---- S^T = K . Q^T : st0 keys kb..kb+15 (row=l16*4+j), st1 +16 ----
        f32x4 st0 = f32x4{0.f, 0.f, 0.f, 0.f}, st1 = st0;
        __builtin_amdgcn_s_setprio(1);
#pragma unroll
        for (int ds = 0; ds < 2; ++ds) {
          const int slot = ((ds * 4 + l16) ^ (l15 & 7)) * 8;
          bf16x8 ak0 = *(const bf16x8*)&Ksb[(c * 32 + l15) * 64 + slot];
          st0 = MFMA16(ak0, bq[ds], st0);
          bf16x8 ak1 = *(const bf16x8*)&Ksb[(c * 32 + 16 + l15) * 64 + slot];
          st1 = MFMA16(ak1, bq[ds], st1);
        }
        __builtin_amdgcn_s_setprio(0);

        // ---- mask + lane-partial max ----
        float tl;
        if (kb + 31 > qstart) {
#pragma unroll
          for (int j = 0; j < 4; ++j) {
            const int key = kb + l16 * 4 + j;
            st0[j] = (key <= qv) ? st0[j] : -3e38f;
            st1[j] = (key + 16 <= qv) ? st1[j] : -3e38f;
          }
        }
        tl = fmaxf(fmaxf(fmaxf(st0[0], st0[1]), fmaxf(st0[2], st0[3])),
                   fmaxf(fmaxf(st1[0], st1[1]), fmaxf(st1[2], st1[3])));

        // ---- defer-max ----
        float mn;
        if (__all(tl <= mrow + 8.0f)) {
          mn = mrow;
        } else {
          float tj = fmaxf(tl, __shfl_xor(tl, 16, 64));
          tj = fmaxf(tj, __shfl_xor(tj, 32, 64));
          mn = fmaxf(mrow, tj);
          const float al = exp2f(mrow - mn);
          mrow = mn;
          lrowh *= al;
#pragma unroll
          for (int i = 0; i < 4; ++i)
#pragma unroll
            for (int j = 0; j < 4; ++j) acc[i][j] *= al;
        }

        // ---- exp in place + lane-partial sum ----
#pragma unroll
        for (int j = 0; j < 4; ++j) {
          st0[j] = exp2f(st0[j] - mn);
          st1[j] = exp2f(st1[j] - mn);
        }
        lrowh += ((st0[0] + st0[1]) + (st0[2] + st0[3])) +
                 ((st1[0] + st1[1]) + (st1[2] + st1[3]));

        // ---- P pack: lane owns q=l15; needs keys l16*8..+7 as B-frag ----
        // sources: l16<2 -> st0-packs of groups {2*(l16&1), +1};
        //          l16>=2 -> st1-packs of same groups.
        const unsigned a0  = pkbf(st0[0], st0[1]), a0b = pkbf(st0[2], st0[3]);
        const unsigned a1  = pkbf(st1[0], st1[1]), a1b = pkbf(st1[2], st1[3]);
        const unsigned sA0  = __shfl(a0, srcA, 64),  sA0b = __shfl(a0b, srcA, 64);
        const unsigned sB0  = __shfl(a0, srcB, 64),  sB0b = __shfl(a0b, srcB, 64);
        const unsigned sA1  = __shfl(a1, srcA, 64),  sA1b = __shfl(a1b, srcA, 64);
        const unsigned sB1  = __shfl(a1, srcB, 64),  sB1b = __shfl(a1b, srcB, 64);
        U4 f;
        f.u[0] = lo16 ? sA0 : sA1;  f.u[1] = lo16 ? sA0b : sA1b;
        f.u[2] = lo16 ? sB0 : sB1;  f.u[3] = lo16 ? sB0b : sB1b;

        // ---- O^T += V^T . P ----
        __builtin_amdgcn_s_setprio(1);
#pragma unroll
        for (int dg = 0; dg < 4; ++dg) {
          const int d = dg * 16 + l15;
          const int addr = d * 32 + ((c * 16 + l16 * 4) ^ ((((d & 7) ^ (d >> 3))) << 2));
          const bf16x8 vf = *(const bf16x8*)&Vtb[addr];
          acc[dg] = MFMA16(vf, f.v, acc[dg]);
        }
        __builtin_amdgcn_s_setprio(0);
      }
    }

    // ---- epilogue: reduce l over l16 groups; write O^T rows ----
    float l2 = lrowh + __shfl_xor(lrowh, 16, 64);
    const float lrow = l2 + __shfl_xor(l2, 32, 64);
    const float rl = 1.0f / lrow;
    u16* orow = ctx + ((size_t)bb * kS + (qstart + l15)) * kD + hh * 64;
#pragma unroll
    for (int dg = 0; dg < 4; ++dg) {
      u16x4 pk;
#pragma unroll
      for (int j = 0; j < 4; ++j) pk[j] = f2bf(acc[dg][j] * rl);
      *(u16x4*)&orow[dg * 16 + l16 * 4] = pk;
    }
  }
}

// ---------------- launcher ----------------
extern "C" void kernel_launch(void* const* d_in, const int* in_sizes, int n_in,
                              void* d_out, int out_size, void* d_ws, size_t ws_size,
                              hipStream_t stream) {
  const float* x     = (const float*)d_in[0];
  const float* w_qkv = (const float*)d_in[1];
  const float* w_out = (const float*)d_in[2];
  float* out = (float*)d_out;

  u16* ws    = (u16*)d_ws;
  u16* x_bf  = ws;                                  // 8192*1024
  u16* wqkvT = x_bf + (size_t)M1 * K1;              // 3072*1024
  u16* woutT = wqkvT + (size_t)N1 * K1;             // 1024*1024
  u16* qkv   = woutT + (size_t)kD * kD;             // 3 * 64*2048*64
  u16* ctx   = qkv + (size_t)3 * kB * kH * kS * kHD;  // 8192*1024

  k_cast_x<<<M1 * K1 / 1024, 256, 0, stream>>>(x, x_bf);
  k_transpose_cast<<<dim3(N1 / 32, K1 / 32), 256, 0, stream>>>(w_qkv, wqkvT, K1, N1);
  k_transpose_cast<<<dim3(kD / 32, kD / 32), 256, 0, stream>>>(w_out, woutT, kD, kD);

  k_gemm_bt<0><<<dim3(N1 / 128, M1 / 128), 256, 0, stream>>>(x_bf, wqkvT, qkv, nullptr,
                                                             M1, N1, K1);

  const u16* Qg = qkv;
  const u16* Kg = qkv + (size_t)kB * kH * kS * kHD;
  const u16* Vg = qkv + (size_t)2 * kB * kH * kS * kHD;
  k_attn<<<dim3(512), 512, 0, stream>>>(Qg, Kg, Vg, ctx);

  k_gemm_bt<1><<<dim3(kD / 128, M1 / 128), 256, 0, stream>>>(ctx, woutT, nullptr, out,
                                                             M1, kD, K1);
}